// Round 3
// baseline (197.237 us; speedup 1.0000x reference)
//
#include <hip/hip_runtime.h>

// B=32, C=1, H=512, W=512 fp32. Haar DWT is linear:
// (i_X - t_X) = DWT_X(input - target) -> single fused pass.
// R2: merge finalize into the main kernel via last-block-done (release
// fetch_add on a counter; last block acquires and reduces all partials).
// One kernel node + one 4-byte memset node. Agent-scope atomics for
// cross-XCD safety (G16).

#define HH 512
#define WW 512
#define NBLK 4096
static constexpr float N_LOW = 2097152.0f;  // 32 * 256 * 256

__global__ __launch_bounds__(256) void haar_loss_kernel(
    const float* __restrict__ inp, const float* __restrict__ tgt,
    float* __restrict__ ws, float* __restrict__ out)
{
    const int idx = blockIdx.x * 256 + threadIdx.x;
    const int c4 = idx & 127;          // group of 4 columns
    const int r  = (idx >> 7) & 255;   // row-pair index
    const int b  = idx >> 15;          // batch
    const int base0 = b * (HH * WW) + (2 * r) * WW + 4 * c4;

    const float4 i0 = *(const float4*)(inp + base0);
    const float4 i1 = *(const float4*)(inp + base0 + WW);
    const float4 t0 = *(const float4*)(tgt + base0);
    const float4 t1 = *(const float4*)(tgt + base0 + WW);

    float sl = 0.f, sh = 0.f;
    {
        const float da = i0.x - t0.x, db = i0.y - t0.y;
        const float dc = i1.x - t1.x, dd = i1.y - t1.y;
        sl += fabsf(0.5f * ( da + db + dc + dd));
        sh += fabsf(0.5f * (-da - db + dc + dd))
            + fabsf(0.5f * (-da + db - dc + dd))
            + fabsf(0.5f * ( da - db - dc + dd));
    }
    {
        const float da = i0.z - t0.z, db = i0.w - t0.w;
        const float dc = i1.z - t1.z, dd = i1.w - t1.w;
        sl += fabsf(0.5f * ( da + db + dc + dd));
        sh += fabsf(0.5f * (-da - db + dc + dd))
            + fabsf(0.5f * (-da + db - dc + dd))
            + fabsf(0.5f * ( da - db - dc + dd));
    }

    // wave-64 butterfly reduce
    #pragma unroll
    for (int off = 32; off > 0; off >>= 1) {
        sl += __shfl_down(sl, off, 64);
        sh += __shfl_down(sh, off, 64);
    }

    __shared__ float red[8];  // 4 waves x {low, high}
    __shared__ bool amLast;
    const int lane = threadIdx.x & 63;
    const int wave = threadIdx.x >> 6;
    if (lane == 0) { red[wave] = sl; red[4 + wave] = sh; }
    __syncthreads();
    if (threadIdx.x == 0) {
        const float tl = red[0] + red[1] + red[2] + red[3];
        const float th = red[4] + red[5] + red[6] + red[7];
        // ws layout: [0..NBLK) low partials, [NBLK..2*NBLK) high, ws[2*NBLK] counter
        __hip_atomic_store(&ws[blockIdx.x],        tl, __ATOMIC_RELAXED, __HIP_MEMORY_SCOPE_AGENT);
        __hip_atomic_store(&ws[NBLK + blockIdx.x], th, __ATOMIC_RELAXED, __HIP_MEMORY_SCOPE_AGENT);
        unsigned old = __hip_atomic_fetch_add((unsigned*)(ws + 2 * NBLK), 1u,
                                              __ATOMIC_ACQ_REL, __HIP_MEMORY_SCOPE_AGENT);
        amLast = (old == NBLK - 1);
    }
    __syncthreads();

    if (amLast) {
        float sl2 = 0.f, sh2 = 0.f;
        for (int i = threadIdx.x; i < NBLK; i += 256) {
            sl2 += __hip_atomic_load(&ws[i],        __ATOMIC_RELAXED, __HIP_MEMORY_SCOPE_AGENT);
            sh2 += __hip_atomic_load(&ws[NBLK + i], __ATOMIC_RELAXED, __HIP_MEMORY_SCOPE_AGENT);
        }
        #pragma unroll
        for (int off = 32; off > 0; off >>= 1) {
            sl2 += __shfl_down(sl2, off, 64);
            sh2 += __shfl_down(sh2, off, 64);
        }
        __syncthreads();  // before red[] reuse
        if (lane == 0) { red[wave] = sl2; red[4 + wave] = sh2; }
        __syncthreads();
        if (threadIdx.x == 0) {
            out[0] = (red[0] + red[1] + red[2] + red[3]) / N_LOW;
            out[1] = (red[4] + red[5] + red[6] + red[7]) / (3.0f * N_LOW);
        }
    }
}

extern "C" void kernel_launch(void* const* d_in, const int* in_sizes, int n_in,
                              void* d_out, int out_size, void* d_ws, size_t ws_size,
                              hipStream_t stream) {
    const float* inp = (const float*)d_in[0];
    const float* tgt = (const float*)d_in[1];
    float* out = (float*)d_out;
    float* ws  = (float*)d_ws;

    // Zero only the 4-byte done-counter (ws re-poisoned to 0xAA each launch).
    hipMemsetAsync(ws + 2 * NBLK, 0, sizeof(unsigned), stream);
    haar_loss_kernel<<<NBLK, 256, 0, stream>>>(inp, tgt, ws, out);
}

// Round 4
// 92.778 us; speedup vs baseline: 2.1259x; 2.1259x over previous
//
#include <hip/hip_runtime.h>

// B=32, C=1, H=512, W=512 fp32. Haar DWT is linear:
// (i_X - t_X) = DWT_X(input - target) -> single fused pass.
//
// R3 post-mortem: last-block-done with acq_rel agent-scope fetch_add on one
// address = ~140us serialization cliff (L2 wb/inv across 8 XCDs per op).
// R4: revert to R1's two-kernel tree reduce (plain stores, zero atomics),
// plus: 2048 blocks x 2 patches/thread (8 float4 loads in flight) and a
// 1024-thread finalize (shorter latency chain).

#define HH 512
#define WW 512
#define NBLK 2048
#define STRIDE_ITEMS 524288   // NBLK * 256
static constexpr float N_LOW = 2097152.0f;  // 32 * 256 * 256

__device__ __forceinline__ void accum_patch(
    const float* __restrict__ inp, const float* __restrict__ tgt,
    int idx, float& sl, float& sh)
{
    const int c4 = idx & 127;          // group of 4 columns
    const int r  = (idx >> 7) & 255;   // row-pair index
    const int b  = idx >> 15;          // batch
    const int base0 = b * (HH * WW) + (2 * r) * WW + 4 * c4;

    const float4 i0 = *(const float4*)(inp + base0);
    const float4 i1 = *(const float4*)(inp + base0 + WW);
    const float4 t0 = *(const float4*)(tgt + base0);
    const float4 t1 = *(const float4*)(tgt + base0 + WW);

    {
        const float da = i0.x - t0.x, db = i0.y - t0.y;
        const float dc = i1.x - t1.x, dd = i1.y - t1.y;
        sl += fabsf(0.5f * ( da + db + dc + dd));
        sh += fabsf(0.5f * (-da - db + dc + dd))
            + fabsf(0.5f * (-da + db - dc + dd))
            + fabsf(0.5f * ( da - db - dc + dd));
    }
    {
        const float da = i0.z - t0.z, db = i0.w - t0.w;
        const float dc = i1.z - t1.z, dd = i1.w - t1.w;
        sl += fabsf(0.5f * ( da + db + dc + dd));
        sh += fabsf(0.5f * (-da - db + dc + dd))
            + fabsf(0.5f * (-da + db - dc + dd))
            + fabsf(0.5f * ( da - db - dc + dd));
    }
}

__global__ __launch_bounds__(256) void haar_loss_kernel(
    const float* __restrict__ inp, const float* __restrict__ tgt,
    float* __restrict__ ws)
{
    const int idx = blockIdx.x * 256 + threadIdx.x;

    float sl = 0.f, sh = 0.f;
    accum_patch(inp, tgt, idx,                sl, sh);
    accum_patch(inp, tgt, idx + STRIDE_ITEMS, sl, sh);

    // wave-64 butterfly reduce
    #pragma unroll
    for (int off = 32; off > 0; off >>= 1) {
        sl += __shfl_down(sl, off, 64);
        sh += __shfl_down(sh, off, 64);
    }

    __shared__ float red[8];  // 4 waves x {low, high}
    const int lane = threadIdx.x & 63;
    const int wave = threadIdx.x >> 6;
    if (lane == 0) { red[wave] = sl; red[4 + wave] = sh; }
    __syncthreads();
    if (threadIdx.x == 0) {
        // SoA partials: ws[0..NBLK) = low, ws[NBLK..2*NBLK) = high.
        ws[blockIdx.x]        = red[0] + red[1] + red[2] + red[3];
        ws[NBLK + blockIdx.x] = red[4] + red[5] + red[6] + red[7];
    }
}

__global__ __launch_bounds__(1024) void haar_finalize_kernel(
    const float* __restrict__ ws, float* __restrict__ out)
{
    const int tid = threadIdx.x;
    // 2048 low + 2048 high partials; 1024 threads -> 2 loads each stream.
    float sl = ws[tid] + ws[tid + 1024];
    float sh = ws[NBLK + tid] + ws[NBLK + tid + 1024];

    #pragma unroll
    for (int off = 32; off > 0; off >>= 1) {
        sl += __shfl_down(sl, off, 64);
        sh += __shfl_down(sh, off, 64);
    }
    __shared__ float red[32];  // 16 waves x {low, high}
    const int lane = tid & 63;
    const int wave = tid >> 6;
    if (lane == 0) { red[wave] = sl; red[16 + wave] = sh; }
    __syncthreads();
    if (tid == 0) {
        float tl = 0.f, th = 0.f;
        #pragma unroll
        for (int i = 0; i < 16; ++i) { tl += red[i]; th += red[16 + i]; }
        out[0] = tl / N_LOW;
        out[1] = th / (3.0f * N_LOW);
    }
}

extern "C" void kernel_launch(void* const* d_in, const int* in_sizes, int n_in,
                              void* d_out, int out_size, void* d_ws, size_t ws_size,
                              hipStream_t stream) {
    const float* inp = (const float*)d_in[0];
    const float* tgt = (const float*)d_in[1];
    float* out = (float*)d_out;
    float* ws  = (float*)d_ws;

    // ws[0..2*NBLK) fully written by haar_loss_kernel — no memset required.
    haar_loss_kernel<<<NBLK, 256, 0, stream>>>(inp, tgt, ws);
    haar_finalize_kernel<<<1, 1024, 0, stream>>>(ws, out);
}